// Round 7
// baseline (877.881 us; speedup 1.0000x reference)
//
#include <hip/hip_runtime.h>
#include <hip/hip_bf16.h>

// ChildSumTreeLSTM on MI355X — round 7: fix the latency bind.
// Round-6 counters: Occupancy 12% (1 wave/SIMD), MfmaUtil 1.25%, VALU 1.9%,
// HBM 3.3% -> pure latency-bound. This round: 1024-thread blocks (16 waves/CU,
// 4/SIMD), GRID=256 coop; GEMM tile 256x128 (4x4 waves, 64x32 each).

#define NN   4096
#define MEM  512
#define KD   512
#define GRID 256
#define TFN  1024      // tree_fused threads per block
#define PTHR 256       // prep threads per block

typedef __attribute__((ext_vector_type(8))) short bf16x8;
typedef __attribute__((ext_vector_type(4))) float f32x4;

static __device__ __forceinline__ unsigned short f2bf(float f) {
    union { float f; unsigned int u; } v; v.f = f;
    unsigned int r = v.u + 0x7FFF + ((v.u >> 16) & 1);   // RTN-even
    return (unsigned short)(r >> 16);
}
static __device__ __forceinline__ float sigmoidf_(float x) {
    return 1.0f / (1.0f + __expf(-x));
}

// ---------------- grid barrier (device-scope atomics) -----------------------
static __device__ __forceinline__ void grid_barrier(unsigned int* cnt,
                                                    unsigned int* gen) {
    __syncthreads();
    if (threadIdx.x == 0) {
        unsigned int g = __hip_atomic_load(gen, __ATOMIC_RELAXED,
                                           __HIP_MEMORY_SCOPE_AGENT);
        unsigned int arrived = __hip_atomic_fetch_add(cnt, 1u, __ATOMIC_ACQ_REL,
                                                      __HIP_MEMORY_SCOPE_AGENT);
        if (arrived == (unsigned int)(GRID - 1)) {
            __hip_atomic_store(cnt, 0u, __ATOMIC_RELAXED,
                               __HIP_MEMORY_SCOPE_AGENT);
            __hip_atomic_fetch_add(gen, 1u, __ATOMIC_ACQ_REL,
                                   __HIP_MEMORY_SCOPE_AGENT);
        } else {
            while (__hip_atomic_load(gen, __ATOMIC_ACQUIRE,
                                     __HIP_MEMORY_SCOPE_AGENT) == g) {
                __builtin_amdgcn_s_sleep(1);
            }
        }
    }
    __syncthreads();
}

// ---------------- prep (256-thr blocks) -------------------------------------
__global__ __launch_bounds__(256) void prep(
    const float* __restrict__ inputs,
    const float* __restrict__ Wx, const float* __restrict__ Ws,
    const float* __restrict__ Wf,
    unsigned short* __restrict__ Xb, unsigned short* __restrict__ WxT,
    unsigned short* __restrict__ W2T,
    float* __restrict__ cbuf, unsigned short* __restrict__ hb,
    unsigned int* __restrict__ bar)
{
    const int blk = blockIdx.x, tid = threadIdx.x;
    if (blk >= 512) {
        if (blk < 1536) {
            size_t base = (size_t)(blk - 512) * 2048 + (size_t)tid * 8;
            f32x4 v0 = *(const f32x4*)(inputs + base);
            f32x4 v1 = *(const f32x4*)(inputs + base + 4);
            bf16x8 o;
            o[0] = f2bf(v0[0]); o[1] = f2bf(v0[1]); o[2] = f2bf(v0[2]); o[3] = f2bf(v0[3]);
            o[4] = f2bf(v1[0]); o[5] = f2bf(v1[1]); o[6] = f2bf(v1[2]); o[7] = f2bf(v1[3]);
            *(bf16x8*)(Xb + base) = o;
        } else {
            cbuf[(size_t)NN * MEM + tid * 2]     = 0.0f;
            cbuf[(size_t)NN * MEM + tid * 2 + 1] = 0.0f;
            hb[(size_t)NN * MEM + tid * 2]     = 0;
            hb[(size_t)NN * MEM + tid * 2 + 1] = 0;
            if (tid < 8) bar[tid] = 0u;          // barrier cnt/gen
        }
        return;
    }
    __shared__ float tile[64][65];
    const float* src; unsigned short* dst; int ncols, n0, k0;
    if (blk < 256)      { src = Wx; dst = WxT; ncols = 2048;
                          n0 = (blk & 31) * 64; k0 = (blk >> 5) * 64; }
    else if (blk < 320) { int t2 = blk - 256; src = Wf; dst = W2T; ncols = 512;
                          n0 = (t2 & 7) * 64; k0 = (t2 >> 3) * 64; }
    else                { int t3 = blk - 320; src = Ws; dst = W2T + (size_t)512 * KD;
                          ncols = 1536; n0 = (t3 % 24) * 64; k0 = (t3 / 24) * 64; }
    const int kr = tid >> 4, nc = (tid & 15) * 4;
#pragma unroll
    for (int s = 0; s < 4; ++s) {
        f32x4 v = *(const f32x4*)(src + (size_t)(k0 + kr + s * 16) * ncols + n0 + nc);
        tile[kr + s * 16][nc + 0] = v[0];
        tile[kr + s * 16][nc + 1] = v[1];
        tile[kr + s * 16][nc + 2] = v[2];
        tile[kr + s * 16][nc + 3] = v[3];
    }
    __syncthreads();
    const int r = tid >> 2, kq = (tid & 3) * 16;
    bf16x8 o0, o1;
#pragma unroll
    for (int j = 0; j < 8; ++j) o0[j] = (short)f2bf(tile[kq + j][r]);
#pragma unroll
    for (int j = 0; j < 8; ++j) o1[j] = (short)f2bf(tile[kq + 8 + j][r]);
    unsigned short* drow = dst + (size_t)(n0 + r) * KD + k0 + kq;
    *(bf16x8*)drow = o0;
    *(bf16x8*)(drow + 8) = o1;
}

// ---------------- 256x128 MFMA tile (K=512), 1024 threads -------------------
// 16 waves as 4(M) x 4(N); per-wave 64x32 output = acc[4][2].
// AMODE 0: A row r = Abf[bm+r]              (rows in range; M % 256 == 0)
// AMODE 1: A row r = hb[children[lo + (bm+r)/4][(bm+r)%4]], sentinel if >= M
template <int AMODE>
static __device__ __forceinline__ void gemm_tile(
    const unsigned short* __restrict__ Abf,
    const unsigned short* __restrict__ Bt,
    const float* __restrict__ bias,
    float* __restrict__ C,
    const int* __restrict__ children, int lo, int M,
    int bm, int bn, char* As, char* Bs)
{
    const int tid = threadIdx.x;
    const int wave = tid >> 6, lane = tid & 63;
    const int wm = (wave >> 2) * 64;          // 0,64,128,192
    const int wn = (wave & 3) * 32;           // 0,32,64,96

    f32x4 acc[4][2];
#pragma unroll
    for (int a = 0; a < 4; ++a)
#pragma unroll
        for (int b = 0; b < 2; ++b) acc[a][b] = (f32x4){0.f, 0.f, 0.f, 0.f};

    // A: 256x64 elems = 2048 chunks (2/thread); B: 128x64 = 1024 chunks (1/thread)
    int rowA0 = tid >> 3,            kcA0 = (tid & 7) * 8;
    int rowA1 = (tid + 1024) >> 3,   kcA1 = kcA0;
    int rowB  = rowA0 & 127;         // tid>>3 for tid<1024 gives 0..127
    int kidA0, kidA1;
    if (AMODE == 0) {
        kidA0 = bm + rowA0;
        kidA1 = bm + rowA1;
    } else {
        int f0 = bm + rowA0, f1 = bm + rowA1;
        kidA0 = (f0 < M) ? children[(size_t)(lo + (f0 >> 2)) * 4 + (f0 & 3)] : NN;
        kidA1 = (f1 < M) ? children[(size_t)(lo + (f1 >> 2)) * 4 + (f1 & 3)] : NN;
    }

    for (int k0 = 0; k0 < KD; k0 += 64) {
        bf16x8 a0 = *(const bf16x8*)(Abf + (size_t)kidA0 * KD + k0 + kcA0);
        bf16x8 a1 = *(const bf16x8*)(Abf + (size_t)kidA1 * KD + k0 + kcA1);
        bf16x8 b0 = *(const bf16x8*)(Bt + (size_t)(bn + rowB) * KD + k0 + kcA0);
        __syncthreads();
        *(bf16x8*)(As + ((rowA0 * 128 + kcA0 * 2) ^ ((rowA0 & 7) << 4))) = a0;
        *(bf16x8*)(As + ((rowA1 * 128 + kcA1 * 2) ^ ((rowA1 & 7) << 4))) = a1;
        *(bf16x8*)(Bs + ((rowB * 128 + kcA0 * 2) ^ ((rowB & 7) << 4))) = b0;
        __syncthreads();
#pragma unroll
        for (int ks = 0; ks < 2; ++ks) {
            const int kbyte = (ks * 32 + (lane >> 4) * 8) * 2;
            bf16x8 af[4], bfr[2];
#pragma unroll
            for (int mi = 0; mi < 4; ++mi) {
                int r = wm + mi * 16 + (lane & 15);
                af[mi] = *(const bf16x8*)(As + ((r * 128 + kbyte) ^ ((r & 7) << 4)));
            }
#pragma unroll
            for (int ni = 0; ni < 2; ++ni) {
                int r = wn + ni * 16 + (lane & 15);
                bfr[ni] = *(const bf16x8*)(Bs + ((r * 128 + kbyte) ^ ((r & 7) << 4)));
            }
#pragma unroll
            for (int mi = 0; mi < 4; ++mi)
#pragma unroll
                for (int ni = 0; ni < 2; ++ni)
                    acc[mi][ni] = __builtin_amdgcn_mfma_f32_16x16x32_bf16(
                        af[mi], bfr[ni], acc[mi][ni], 0, 0, 0);
        }
    }

    float bv[2];
#pragma unroll
    for (int ni = 0; ni < 2; ++ni)
        bv[ni] = bias ? bias[bn + wn + ni * 16 + (lane & 15)] : 0.0f;
#pragma unroll
    for (int mi = 0; mi < 4; ++mi) {
#pragma unroll
        for (int j = 0; j < 4; ++j) {
            int r = bm + wm + mi * 16 + (lane >> 4) * 4 + j;
            if (r < M) {
                float* crow = C + (size_t)r * 2048 + bn + wn + (lane & 15);
#pragma unroll
                for (int ni = 0; ni < 2; ++ni)
                    crow[ni * 16] = acc[mi][ni][j] + bv[ni];
            }
        }
    }
}

// ---------------- elementwise bodies ----------------------------------------
static __device__ __forceinline__ void leaf_body(
    int u, const float* __restrict__ XW, const float* __restrict__ bs,
    float* __restrict__ cbuf, unsigned short* __restrict__ hb)
{
    int n = u >> 7, d4 = (u & 127) << 2;
    const float* xwr = XW + (size_t)n * 2048;
    f32x4 ix = *(const f32x4*)(xwr + d4);
    f32x4 ox = *(const f32x4*)(xwr + 1024 + d4);
    f32x4 ux = *(const f32x4*)(xwr + 1536 + d4);
    f32x4 bi = *(const f32x4*)(bs + d4);
    f32x4 bo = *(const f32x4*)(bs + 512 + d4);
    f32x4 bu = *(const f32x4*)(bs + 1024 + d4);
    f32x4 c4; ushort4 h4;
#pragma unroll
    for (int j = 0; j < 4; ++j) {
        float ig = sigmoidf_(ix[j] + bi[j]);
        float og = sigmoidf_(ox[j] + bo[j]);
        float ug = tanhf(ux[j] + bu[j]);
        float c = ig * ug;
        c4[j] = c;
        ((unsigned short*)&h4)[j] = f2bf(og * tanhf(c));
    }
    *(f32x4*)(cbuf + (size_t)n * MEM + d4) = c4;
    *(ushort4*)(hb + (size_t)n * MEM + d4) = h4;
}

static __device__ __forceinline__ void update_body(
    int u, int lo, const float* __restrict__ XW, const float* __restrict__ G,
    const float* __restrict__ bs, const float* __restrict__ bfv,
    const int* __restrict__ children, float* __restrict__ cbuf,
    unsigned short* __restrict__ hb, float* __restrict__ out)
{
    int i = u >> 7, d4 = (u & 127) << 2;
    int n = lo + i;
    const float* xwr = XW + (size_t)n * 2048;
    f32x4 ix = *(const f32x4*)(xwr + d4);
    f32x4 fx = *(const f32x4*)(xwr + 512 + d4);
    f32x4 ox = *(const f32x4*)(xwr + 1024 + d4);
    f32x4 ux = *(const f32x4*)(xwr + 1536 + d4);
    const float* g0 = G + (size_t)(4 * i) * 2048 + d4;
    const int* kk = children + (size_t)n * 4;
    f32x4 fp[4], cc[4];
    f32x4 is4 = {0, 0, 0, 0}, os4 = {0, 0, 0, 0}, us4 = {0, 0, 0, 0};
#pragma unroll
    for (int k = 0; k < 4; ++k) {
        const float* gr = g0 + (size_t)k * 2048;
        fp[k] = *(const f32x4*)gr;
        is4 += *(const f32x4*)(gr + 512);
        os4 += *(const f32x4*)(gr + 1024);
        us4 += *(const f32x4*)(gr + 1536);
        cc[k] = *(const f32x4*)(cbuf + (size_t)kk[k] * MEM + d4);
    }
    f32x4 bi = *(const f32x4*)(bs + d4);
    f32x4 bo = *(const f32x4*)(bs + 512 + d4);
    f32x4 bu = *(const f32x4*)(bs + 1024 + d4);
    f32x4 bff = *(const f32x4*)(bfv + d4);
    f32x4 c4, hout; ushort4 h4;
#pragma unroll
    for (int j = 0; j < 4; ++j) {
        float ig = sigmoidf_(ix[j] + is4[j] + bi[j]);
        float og = sigmoidf_(ox[j] + os4[j] + bo[j]);
        float ug = tanhf(ux[j] + us4[j] + bu[j]);
        float c = ig * ug;
#pragma unroll
        for (int k = 0; k < 4; ++k)
            c += sigmoidf_(fp[k][j] + bff[j] + fx[j]) * cc[k][j];
        c4[j] = c;
        float h = og * tanhf(c);
        hout[j] = h;
        ((unsigned short*)&h4)[j] = f2bf(h);
    }
    *(f32x4*)(cbuf + (size_t)n * MEM + d4) = c4;
    *(ushort4*)(hb + (size_t)n * MEM + d4) = h4;
    if (n == NN - 1) *(f32x4*)(out + d4) = hout;
}

// ---------------- cooperative fused kernel (1024 thr) -----------------------
__global__ __launch_bounds__(1024, 4) void tree_fused(
    const unsigned short* __restrict__ Xb, const unsigned short* __restrict__ WxT,
    const float* __restrict__ bx, const unsigned short* __restrict__ W2T,
    const float* __restrict__ bs, const float* __restrict__ bfv,
    const int* __restrict__ children, float* __restrict__ XW, float* __restrict__ G,
    float* __restrict__ cbuf, unsigned short* __restrict__ hb, float* __restrict__ out,
    unsigned int* __restrict__ bar)
{
    __shared__ __align__(16) char As[256 * 64 * 2];
    __shared__ __align__(16) char Bs[128 * 64 * 2];
    unsigned int* bcnt = bar;
    unsigned int* bgen = bar + 1;
    const int wg = blockIdx.x, tid = threadIdx.x;
    const int nwg = gridDim.x;
    const int gid = wg * TFN + tid;
    const int gstride = nwg * TFN;

    // phase 0: XW = Xb @ WxT^T + bx  (16x16 = 256 tiles, 1 per wg)
    for (int t = wg; t < 256; t += nwg) {
        int bm = (t >> 4) * 256, bn = (t & 15) * 128;
        gemm_tile<0>(Xb, WxT, bx, XW, nullptr, 0, NN, bm, bn, As, Bs);
    }
    grid_barrier(bcnt, bgen);

    // phase 1: leaves [0,3072)
    for (int u = gid; u < 3072 * 128; u += gstride)
        leaf_body(u, XW, bs, cbuf, hb);
    grid_barrier(bcnt, bgen);

    const int lvl_lo[6] = {3072, 3755, 4011, 4075, 4091, 4095};
    const int lvl_L[6]  = {683, 256, 64, 16, 4, 1};
    for (int l = 0; l < 6; ++l) {
        const int lo = lvl_lo[l], L = lvl_L[l], M4 = 4 * L;
        const int rt = (M4 + 255) >> 8, ntiles = rt * 16;

        for (int t = wg; t < ntiles; t += nwg) {
            int bm = (t >> 4) * 256, bn = (t & 15) * 128;
            gemm_tile<1>(hb, W2T, nullptr, G, children, lo, M4, bm, bn, As, Bs);
        }
        grid_barrier(bcnt, bgen);

        for (int u = gid; u < L * 128; u += gstride)
            update_body(u, lo, XW, G, bs, bfv, children, cbuf, hb, out);
        grid_barrier(bcnt, bgen);
    }
}

// ---------------- fallback discrete kernels ---------------------------------
__global__ __launch_bounds__(1024) void k_gemm_xw(
    const unsigned short* __restrict__ Xb, const unsigned short* __restrict__ WxT,
    const float* __restrict__ bx, float* __restrict__ XW)
{
    __shared__ __align__(16) char As[256 * 64 * 2];
    __shared__ __align__(16) char Bs[128 * 64 * 2];
    gemm_tile<0>(Xb, WxT, bx, XW, nullptr, 0, NN,
                 blockIdx.y * 256, blockIdx.x * 128, As, Bs);
}

__global__ __launch_bounds__(1024) void k_gemm_g(
    const unsigned short* __restrict__ hb, const unsigned short* __restrict__ W2T,
    float* __restrict__ G, const int* __restrict__ children, int lo, int M4)
{
    __shared__ __align__(16) char As[256 * 64 * 2];
    __shared__ __align__(16) char Bs[128 * 64 * 2];
    gemm_tile<1>(hb, W2T, nullptr, G, children, lo, M4,
                 blockIdx.y * 256, blockIdx.x * 128, As, Bs);
}

__global__ __launch_bounds__(256) void k_leaf(
    const float* __restrict__ XW, const float* __restrict__ bs,
    float* __restrict__ cbuf, unsigned short* __restrict__ hb)
{
    int u = blockIdx.x * blockDim.x + threadIdx.x;
    if (u < 3072 * 128) leaf_body(u, XW, bs, cbuf, hb);
}

__global__ __launch_bounds__(256) void k_update(
    const float* __restrict__ XW, const float* __restrict__ G,
    const float* __restrict__ bs, const float* __restrict__ bfv,
    const int* __restrict__ children, float* __restrict__ cbuf,
    unsigned short* __restrict__ hb, float* __restrict__ out, int lo, int L)
{
    int u = blockIdx.x * blockDim.x + threadIdx.x;
    if (u < L * 128) update_body(u, lo, XW, G, bs, bfv, children, cbuf, hb, out);
}

extern "C" void kernel_launch(void* const* d_in, const int* in_sizes, int n_in,
                              void* d_out, int out_size, void* d_ws, size_t ws_size,
                              hipStream_t stream) {
    const float* inputs   = (const float*)d_in[0];
    const float* Wx       = (const float*)d_in[1];
    const float* bx       = (const float*)d_in[2];
    const float* Ws       = (const float*)d_in[3];
    const float* bs       = (const float*)d_in[4];
    const float* Wf       = (const float*)d_in[5];
    const float* bfv      = (const float*)d_in[6];
    const int*   children = (const int*)d_in[7];
    float* out = (float*)d_out;

    float* XW   = (float*)d_ws;                                   // 4096*2048
    float* G    = XW + (size_t)NN * 2048;                         // 2732*2048
    float* cbuf = G + (size_t)2732 * 2048;                        // 4097*512
    unsigned short* hb  = (unsigned short*)(cbuf + (size_t)(NN + 1) * MEM); // 4097*512
    unsigned short* Xb  = hb + (size_t)(NN + 1) * MEM;            // 4096*512
    unsigned short* WxT = Xb + (size_t)NN * MEM;                  // 2048*512
    unsigned short* W2T = WxT + (size_t)2048 * KD;                // 2048*512
    unsigned int* bar   = (unsigned int*)(W2T + (size_t)2048 * KD);  // 8 u32

    prep<<<1537, PTHR, 0, stream>>>(inputs, Wx, Ws, Wf, Xb, WxT, W2T, cbuf, hb, bar);

    static const int lvl_lo[6] = {3072, 3755, 4011, 4075, 4091, 4095};
    static const int lvl_L[6]  = {683, 256, 64, 16, 4, 1};

    void* args[] = {&Xb, &WxT, &bx, &W2T, &bs, &bfv, &children,
                    &XW, &G, &cbuf, &hb, &out, &bar};
    hipError_t rc = hipLaunchCooperativeKernel((void*)tree_fused, dim3(GRID),
                                               dim3(TFN), args, 0, stream);
    if (rc != hipSuccess) {
        // discrete fallback: same device bodies, separate launches
        k_gemm_xw<<<dim3(16, 16), TFN, 0, stream>>>(Xb, WxT, bx, XW);
        k_leaf<<<(3072 * 128 + 255) / 256, 256, 0, stream>>>(XW, bs, cbuf, hb);
        for (int l = 0; l < 6; ++l) {
            const int lo = lvl_lo[l], L = lvl_L[l], M4 = 4 * L;
            const int rt = (M4 + 255) >> 8;
            k_gemm_g<<<dim3(16, rt), TFN, 0, stream>>>(hb, W2T, G, children, lo, M4);
            k_update<<<(L * 128 + 255) / 256, 256, 0, stream>>>(
                XW, G, bs, bfv, children, cbuf, hb, out, lo, L);
        }
    }
}

// Round 8
// 480.805 us; speedup vs baseline: 1.8259x; 1.8259x over previous
//
#include <hip/hip_runtime.h>
#include <hip/hip_bf16.h>

// ChildSumTreeLSTM on MI355X — round 8: fix the L2-invalidation storm.
// Rounds 5-7 all ~equally slow with ALL counters low because the grid barrier
// polled `gen` with an AGENT-scope ACQUIRE load: on gfx950 every agent-scope
// acquire emits buffer_inv (per-XCD L2 invalidate). 256 blocks polling =
// continuous grid-wide L2 nuke -> all traffic at HBM-latency rates.
// Fix: RELAXED poll (sc1 load, bypasses L2, no invalidate) + ONE acquire
// load after the generation flips. Structure otherwise identical to round 7.

#define NN   4096
#define MEM  512
#define KD   512
#define GRID 256
#define TFN  1024      // tree_fused threads per block
#define PTHR 256       // prep threads per block

typedef __attribute__((ext_vector_type(8))) short bf16x8;
typedef __attribute__((ext_vector_type(4))) float f32x4;

static __device__ __forceinline__ unsigned short f2bf(float f) {
    union { float f; unsigned int u; } v; v.f = f;
    unsigned int r = v.u + 0x7FFF + ((v.u >> 16) & 1);   // RTN-even
    return (unsigned short)(r >> 16);
}
static __device__ __forceinline__ float sigmoidf_(float x) {
    return 1.0f / (1.0f + __expf(-x));
}

// ---------------- grid barrier (device-scope atomics) -----------------------
// Arrival: one ACQ_REL RMW on cnt (release publishes this block's writes;
// the acquire side lets the LAST block see all others' writes via the RMW
// chain). Wait: RELAXED poll (no cache side effects), then ONE acquire load
// of gen to pull in the release of the last block. 1 wb + 2 inv per block
// per barrier instead of one inv per poll iteration.
static __device__ __forceinline__ void grid_barrier(unsigned int* cnt,
                                                    unsigned int* gen) {
    __syncthreads();
    if (threadIdx.x == 0) {
        unsigned int g = __hip_atomic_load(gen, __ATOMIC_RELAXED,
                                           __HIP_MEMORY_SCOPE_AGENT);
        unsigned int arrived = __hip_atomic_fetch_add(cnt, 1u, __ATOMIC_ACQ_REL,
                                                      __HIP_MEMORY_SCOPE_AGENT);
        if (arrived == (unsigned int)(GRID - 1)) {
            __hip_atomic_store(cnt, 0u, __ATOMIC_RELAXED,
                               __HIP_MEMORY_SCOPE_AGENT);
            __hip_atomic_fetch_add(gen, 1u, __ATOMIC_RELEASE,
                                   __HIP_MEMORY_SCOPE_AGENT);
        } else {
            while (__hip_atomic_load(gen, __ATOMIC_RELAXED,
                                     __HIP_MEMORY_SCOPE_AGENT) == g) {
                __builtin_amdgcn_s_sleep(8);
            }
        }
        unsigned int v = __hip_atomic_load(gen, __ATOMIC_ACQUIRE,
                                           __HIP_MEMORY_SCOPE_AGENT);
        asm volatile("" :: "v"(v));   // keep the acquire load live
    }
    __syncthreads();
}

// ---------------- prep (256-thr blocks) -------------------------------------
__global__ __launch_bounds__(256) void prep(
    const float* __restrict__ inputs,
    const float* __restrict__ Wx, const float* __restrict__ Ws,
    const float* __restrict__ Wf,
    unsigned short* __restrict__ Xb, unsigned short* __restrict__ WxT,
    unsigned short* __restrict__ W2T,
    float* __restrict__ cbuf, unsigned short* __restrict__ hb,
    unsigned int* __restrict__ bar)
{
    const int blk = blockIdx.x, tid = threadIdx.x;
    if (blk >= 512) {
        if (blk < 1536) {
            size_t base = (size_t)(blk - 512) * 2048 + (size_t)tid * 8;
            f32x4 v0 = *(const f32x4*)(inputs + base);
            f32x4 v1 = *(const f32x4*)(inputs + base + 4);
            bf16x8 o;
            o[0] = f2bf(v0[0]); o[1] = f2bf(v0[1]); o[2] = f2bf(v0[2]); o[3] = f2bf(v0[3]);
            o[4] = f2bf(v1[0]); o[5] = f2bf(v1[1]); o[6] = f2bf(v1[2]); o[7] = f2bf(v1[3]);
            *(bf16x8*)(Xb + base) = o;
        } else {
            cbuf[(size_t)NN * MEM + tid * 2]     = 0.0f;
            cbuf[(size_t)NN * MEM + tid * 2 + 1] = 0.0f;
            hb[(size_t)NN * MEM + tid * 2]     = 0;
            hb[(size_t)NN * MEM + tid * 2 + 1] = 0;
            if (tid < 8) bar[tid] = 0u;          // barrier cnt/gen
        }
        return;
    }
    __shared__ float tile[64][65];
    const float* src; unsigned short* dst; int ncols, n0, k0;
    if (blk < 256)      { src = Wx; dst = WxT; ncols = 2048;
                          n0 = (blk & 31) * 64; k0 = (blk >> 5) * 64; }
    else if (blk < 320) { int t2 = blk - 256; src = Wf; dst = W2T; ncols = 512;
                          n0 = (t2 & 7) * 64; k0 = (t2 >> 3) * 64; }
    else                { int t3 = blk - 320; src = Ws; dst = W2T + (size_t)512 * KD;
                          ncols = 1536; n0 = (t3 % 24) * 64; k0 = (t3 / 24) * 64; }
    const int kr = tid >> 4, nc = (tid & 15) * 4;
#pragma unroll
    for (int s = 0; s < 4; ++s) {
        f32x4 v = *(const f32x4*)(src + (size_t)(k0 + kr + s * 16) * ncols + n0 + nc);
        tile[kr + s * 16][nc + 0] = v[0];
        tile[kr + s * 16][nc + 1] = v[1];
        tile[kr + s * 16][nc + 2] = v[2];
        tile[kr + s * 16][nc + 3] = v[3];
    }
    __syncthreads();
    const int r = tid >> 2, kq = (tid & 3) * 16;
    bf16x8 o0, o1;
#pragma unroll
    for (int j = 0; j < 8; ++j) o0[j] = (short)f2bf(tile[kq + j][r]);
#pragma unroll
    for (int j = 0; j < 8; ++j) o1[j] = (short)f2bf(tile[kq + 8 + j][r]);
    unsigned short* drow = dst + (size_t)(n0 + r) * KD + k0 + kq;
    *(bf16x8*)drow = o0;
    *(bf16x8*)(drow + 8) = o1;
}

// ---------------- 256x128 MFMA tile (K=512), 1024 threads -------------------
// 16 waves as 4(M) x 4(N); per-wave 64x32 output = acc[4][2].
// AMODE 0: A row r = Abf[bm+r]              (rows in range; M % 256 == 0)
// AMODE 1: A row r = hb[children[lo + (bm+r)/4][(bm+r)%4]], sentinel if >= M
template <int AMODE>
static __device__ __forceinline__ void gemm_tile(
    const unsigned short* __restrict__ Abf,
    const unsigned short* __restrict__ Bt,
    const float* __restrict__ bias,
    float* __restrict__ C,
    const int* __restrict__ children, int lo, int M,
    int bm, int bn, char* As, char* Bs)
{
    const int tid = threadIdx.x;
    const int wave = tid >> 6, lane = tid & 63;
    const int wm = (wave >> 2) * 64;          // 0,64,128,192
    const int wn = (wave & 3) * 32;           // 0,32,64,96

    f32x4 acc[4][2];
#pragma unroll
    for (int a = 0; a < 4; ++a)
#pragma unroll
        for (int b = 0; b < 2; ++b) acc[a][b] = (f32x4){0.f, 0.f, 0.f, 0.f};

    // A: 256x64 elems = 2048 chunks (2/thread); B: 128x64 = 1024 chunks (1/thread)
    int rowA0 = tid >> 3,            kcA0 = (tid & 7) * 8;
    int rowA1 = (tid + 1024) >> 3,   kcA1 = kcA0;
    int rowB  = rowA0 & 127;
    int kidA0, kidA1;
    if (AMODE == 0) {
        kidA0 = bm + rowA0;
        kidA1 = bm + rowA1;
    } else {
        int f0 = bm + rowA0, f1 = bm + rowA1;
        kidA0 = (f0 < M) ? children[(size_t)(lo + (f0 >> 2)) * 4 + (f0 & 3)] : NN;
        kidA1 = (f1 < M) ? children[(size_t)(lo + (f1 >> 2)) * 4 + (f1 & 3)] : NN;
    }

    for (int k0 = 0; k0 < KD; k0 += 64) {
        bf16x8 a0 = *(const bf16x8*)(Abf + (size_t)kidA0 * KD + k0 + kcA0);
        bf16x8 a1 = *(const bf16x8*)(Abf + (size_t)kidA1 * KD + k0 + kcA1);
        bf16x8 b0 = *(const bf16x8*)(Bt + (size_t)(bn + rowB) * KD + k0 + kcA0);
        __syncthreads();
        *(bf16x8*)(As + ((rowA0 * 128 + kcA0 * 2) ^ ((rowA0 & 7) << 4))) = a0;
        *(bf16x8*)(As + ((rowA1 * 128 + kcA1 * 2) ^ ((rowA1 & 7) << 4))) = a1;
        *(bf16x8*)(Bs + ((rowB * 128 + kcA0 * 2) ^ ((rowB & 7) << 4))) = b0;
        __syncthreads();
#pragma unroll
        for (int ks = 0; ks < 2; ++ks) {
            const int kbyte = (ks * 32 + (lane >> 4) * 8) * 2;
            bf16x8 af[4], bfr[2];
#pragma unroll
            for (int mi = 0; mi < 4; ++mi) {
                int r = wm + mi * 16 + (lane & 15);
                af[mi] = *(const bf16x8*)(As + ((r * 128 + kbyte) ^ ((r & 7) << 4)));
            }
#pragma unroll
            for (int ni = 0; ni < 2; ++ni) {
                int r = wn + ni * 16 + (lane & 15);
                bfr[ni] = *(const bf16x8*)(Bs + ((r * 128 + kbyte) ^ ((r & 7) << 4)));
            }
#pragma unroll
            for (int mi = 0; mi < 4; ++mi)
#pragma unroll
                for (int ni = 0; ni < 2; ++ni)
                    acc[mi][ni] = __builtin_amdgcn_mfma_f32_16x16x32_bf16(
                        af[mi], bfr[ni], acc[mi][ni], 0, 0, 0);
        }
    }

    float bv[2];
#pragma unroll
    for (int ni = 0; ni < 2; ++ni)
        bv[ni] = bias ? bias[bn + wn + ni * 16 + (lane & 15)] : 0.0f;
#pragma unroll
    for (int mi = 0; mi < 4; ++mi) {
#pragma unroll
        for (int j = 0; j < 4; ++j) {
            int r = bm + wm + mi * 16 + (lane >> 4) * 4 + j;
            if (r < M) {
                float* crow = C + (size_t)r * 2048 + bn + wn + (lane & 15);
#pragma unroll
                for (int ni = 0; ni < 2; ++ni)
                    crow[ni * 16] = acc[mi][ni][j] + bv[ni];
            }
        }
    }
}

// ---------------- elementwise bodies ----------------------------------------
static __device__ __forceinline__ void leaf_body(
    int u, const float* __restrict__ XW, const float* __restrict__ bs,
    float* __restrict__ cbuf, unsigned short* __restrict__ hb)
{
    int n = u >> 7, d4 = (u & 127) << 2;
    const float* xwr = XW + (size_t)n * 2048;
    f32x4 ix = *(const f32x4*)(xwr + d4);
    f32x4 ox = *(const f32x4*)(xwr + 1024 + d4);
    f32x4 ux = *(const f32x4*)(xwr + 1536 + d4);
    f32x4 bi = *(const f32x4*)(bs + d4);
    f32x4 bo = *(const f32x4*)(bs + 512 + d4);
    f32x4 bu = *(const f32x4*)(bs + 1024 + d4);
    f32x4 c4; ushort4 h4;
#pragma unroll
    for (int j = 0; j < 4; ++j) {
        float ig = sigmoidf_(ix[j] + bi[j]);
        float og = sigmoidf_(ox[j] + bo[j]);
        float ug = tanhf(ux[j] + bu[j]);
        float c = ig * ug;
        c4[j] = c;
        ((unsigned short*)&h4)[j] = f2bf(og * tanhf(c));
    }
    *(f32x4*)(cbuf + (size_t)n * MEM + d4) = c4;
    *(ushort4*)(hb + (size_t)n * MEM + d4) = h4;
}

static __device__ __forceinline__ void update_body(
    int u, int lo, const float* __restrict__ XW, const float* __restrict__ G,
    const float* __restrict__ bs, const float* __restrict__ bfv,
    const int* __restrict__ children, float* __restrict__ cbuf,
    unsigned short* __restrict__ hb, float* __restrict__ out)
{
    int i = u >> 7, d4 = (u & 127) << 2;
    int n = lo + i;
    const float* xwr = XW + (size_t)n * 2048;
    f32x4 ix = *(const f32x4*)(xwr + d4);
    f32x4 fx = *(const f32x4*)(xwr + 512 + d4);
    f32x4 ox = *(const f32x4*)(xwr + 1024 + d4);
    f32x4 ux = *(const f32x4*)(xwr + 1536 + d4);
    const float* g0 = G + (size_t)(4 * i) * 2048 + d4;
    const int* kk = children + (size_t)n * 4;
    f32x4 fp[4], cc[4];
    f32x4 is4 = {0, 0, 0, 0}, os4 = {0, 0, 0, 0}, us4 = {0, 0, 0, 0};
#pragma unroll
    for (int k = 0; k < 4; ++k) {
        const float* gr = g0 + (size_t)k * 2048;
        fp[k] = *(const f32x4*)gr;
        is4 += *(const f32x4*)(gr + 512);
        os4 += *(const f32x4*)(gr + 1024);
        us4 += *(const f32x4*)(gr + 1536);
        cc[k] = *(const f32x4*)(cbuf + (size_t)kk[k] * MEM + d4);
    }
    f32x4 bi = *(const f32x4*)(bs + d4);
    f32x4 bo = *(const f32x4*)(bs + 512 + d4);
    f32x4 bu = *(const f32x4*)(bs + 1024 + d4);
    f32x4 bff = *(const f32x4*)(bfv + d4);
    f32x4 c4, hout; ushort4 h4;
#pragma unroll
    for (int j = 0; j < 4; ++j) {
        float ig = sigmoidf_(ix[j] + is4[j] + bi[j]);
        float og = sigmoidf_(ox[j] + os4[j] + bo[j]);
        float ug = tanhf(ux[j] + us4[j] + bu[j]);
        float c = ig * ug;
#pragma unroll
        for (int k = 0; k < 4; ++k)
            c += sigmoidf_(fp[k][j] + bff[j] + fx[j]) * cc[k][j];
        c4[j] = c;
        float h = og * tanhf(c);
        hout[j] = h;
        ((unsigned short*)&h4)[j] = f2bf(h);
    }
    *(f32x4*)(cbuf + (size_t)n * MEM + d4) = c4;
    *(ushort4*)(hb + (size_t)n * MEM + d4) = h4;
    if (n == NN - 1) *(f32x4*)(out + d4) = hout;
}

// ---------------- cooperative fused kernel (1024 thr) -----------------------
__global__ __launch_bounds__(1024, 4) void tree_fused(
    const unsigned short* __restrict__ Xb, const unsigned short* __restrict__ WxT,
    const float* __restrict__ bx, const unsigned short* __restrict__ W2T,
    const float* __restrict__ bs, const float* __restrict__ bfv,
    const int* __restrict__ children, float* __restrict__ XW, float* __restrict__ G,
    float* __restrict__ cbuf, unsigned short* __restrict__ hb, float* __restrict__ out,
    unsigned int* __restrict__ bar)
{
    __shared__ __align__(16) char As[256 * 64 * 2];
    __shared__ __align__(16) char Bs[128 * 64 * 2];
    unsigned int* bcnt = bar;
    unsigned int* bgen = bar + 1;
    const int wg = blockIdx.x, tid = threadIdx.x;
    const int nwg = gridDim.x;
    const int gid = wg * TFN + tid;
    const int gstride = nwg * TFN;

    // phase 0: XW = Xb @ WxT^T + bx  (16x16 = 256 tiles, 1 per wg)
    for (int t = wg; t < 256; t += nwg) {
        int bm = (t >> 4) * 256, bn = (t & 15) * 128;
        gemm_tile<0>(Xb, WxT, bx, XW, nullptr, 0, NN, bm, bn, As, Bs);
    }
    grid_barrier(bcnt, bgen);

    // phase 1: leaves [0,3072)
    for (int u = gid; u < 3072 * 128; u += gstride)
        leaf_body(u, XW, bs, cbuf, hb);
    grid_barrier(bcnt, bgen);

    const int lvl_lo[6] = {3072, 3755, 4011, 4075, 4091, 4095};
    const int lvl_L[6]  = {683, 256, 64, 16, 4, 1};
    for (int l = 0; l < 6; ++l) {
        const int lo = lvl_lo[l], L = lvl_L[l], M4 = 4 * L;
        const int rt = (M4 + 255) >> 8, ntiles = rt * 16;

        for (int t = wg; t < ntiles; t += nwg) {
            int bm = (t >> 4) * 256, bn = (t & 15) * 128;
            gemm_tile<1>(hb, W2T, nullptr, G, children, lo, M4, bm, bn, As, Bs);
        }
        grid_barrier(bcnt, bgen);

        for (int u = gid; u < L * 128; u += gstride)
            update_body(u, lo, XW, G, bs, bfv, children, cbuf, hb, out);
        grid_barrier(bcnt, bgen);
    }
}

// ---------------- fallback discrete kernels ---------------------------------
__global__ __launch_bounds__(1024) void k_gemm_xw(
    const unsigned short* __restrict__ Xb, const unsigned short* __restrict__ WxT,
    const float* __restrict__ bx, float* __restrict__ XW)
{
    __shared__ __align__(16) char As[256 * 64 * 2];
    __shared__ __align__(16) char Bs[128 * 64 * 2];
    gemm_tile<0>(Xb, WxT, bx, XW, nullptr, 0, NN,
                 blockIdx.y * 256, blockIdx.x * 128, As, Bs);
}

__global__ __launch_bounds__(1024) void k_gemm_g(
    const unsigned short* __restrict__ hb, const unsigned short* __restrict__ W2T,
    float* __restrict__ G, const int* __restrict__ children, int lo, int M4)
{
    __shared__ __align__(16) char As[256 * 64 * 2];
    __shared__ __align__(16) char Bs[128 * 64 * 2];
    gemm_tile<1>(hb, W2T, nullptr, G, children, lo, M4,
                 blockIdx.y * 256, blockIdx.x * 128, As, Bs);
}

__global__ __launch_bounds__(256) void k_leaf(
    const float* __restrict__ XW, const float* __restrict__ bs,
    float* __restrict__ cbuf, unsigned short* __restrict__ hb)
{
    int u = blockIdx.x * blockDim.x + threadIdx.x;
    if (u < 3072 * 128) leaf_body(u, XW, bs, cbuf, hb);
}

__global__ __launch_bounds__(256) void k_update(
    const float* __restrict__ XW, const float* __restrict__ G,
    const float* __restrict__ bs, const float* __restrict__ bfv,
    const int* __restrict__ children, float* __restrict__ cbuf,
    unsigned short* __restrict__ hb, float* __restrict__ out, int lo, int L)
{
    int u = blockIdx.x * blockDim.x + threadIdx.x;
    if (u < L * 128) update_body(u, lo, XW, G, bs, bfv, children, cbuf, hb, out);
}

extern "C" void kernel_launch(void* const* d_in, const int* in_sizes, int n_in,
                              void* d_out, int out_size, void* d_ws, size_t ws_size,
                              hipStream_t stream) {
    const float* inputs   = (const float*)d_in[0];
    const float* Wx       = (const float*)d_in[1];
    const float* bx       = (const float*)d_in[2];
    const float* Ws       = (const float*)d_in[3];
    const float* bs       = (const float*)d_in[4];
    const float* Wf       = (const float*)d_in[5];
    const float* bfv      = (const float*)d_in[6];
    const int*   children = (const int*)d_in[7];
    float* out = (float*)d_out;

    float* XW   = (float*)d_ws;                                   // 4096*2048
    float* G    = XW + (size_t)NN * 2048;                         // 2732*2048
    float* cbuf = G + (size_t)2732 * 2048;                        // 4097*512
    unsigned short* hb  = (unsigned short*)(cbuf + (size_t)(NN + 1) * MEM); // 4097*512
    unsigned short* Xb  = hb + (size_t)(NN + 1) * MEM;            // 4096*512
    unsigned short* WxT = Xb + (size_t)NN * MEM;                  // 2048*512
    unsigned short* W2T = WxT + (size_t)2048 * KD;                // 2048*512
    unsigned int* bar   = (unsigned int*)(W2T + (size_t)2048 * KD);  // 8 u32

    prep<<<1537, PTHR, 0, stream>>>(inputs, Wx, Ws, Wf, Xb, WxT, W2T, cbuf, hb, bar);

    static const int lvl_lo[6] = {3072, 3755, 4011, 4075, 4091, 4095};
    static const int lvl_L[6]  = {683, 256, 64, 16, 4, 1};

    void* args[] = {&Xb, &WxT, &bx, &W2T, &bs, &bfv, &children,
                    &XW, &G, &cbuf, &hb, &out, &bar};
    hipError_t rc = hipLaunchCooperativeKernel((void*)tree_fused, dim3(GRID),
                                               dim3(TFN), args, 0, stream);
    if (rc != hipSuccess) {
        // discrete fallback: same device bodies, separate launches
        k_gemm_xw<<<dim3(16, 16), TFN, 0, stream>>>(Xb, WxT, bx, XW);
        k_leaf<<<(3072 * 128 + 255) / 256, 256, 0, stream>>>(XW, bs, cbuf, hb);
        for (int l = 0; l < 6; ++l) {
            const int lo = lvl_lo[l], L = lvl_L[l], M4 = 4 * L;
            const int rt = (M4 + 255) >> 8;
            k_gemm_g<<<dim3(16, rt), TFN, 0, stream>>>(hb, W2T, G, children, lo, M4);
            k_update<<<(L * 128 + 255) / 256, 256, 0, stream>>>(
                XW, G, bs, bfv, children, cbuf, hb, out, lo, L);
        }
    }
}